// Round 11
// baseline (80.855 us; speedup 1.0000x reference)
//
#include <hip/hip_runtime.h>

constexpr int HH = 100;
constexpr int WW = 100;
constexpr int NH = 8;
constexpr int NP = 4;
constexpr int B  = 4;
constexpr int Q  = HH * WW;   // 10000
constexpr int S  = Q;
constexpr int K  = 256;
constexpr int DH = 32;
constexpr int M  = B * Q;     // 40000
constexpr int NTILES = M / 32; // 1250

typedef __attribute__((ext_vector_type(8))) short short8;
typedef __attribute__((ext_vector_type(4))) float f32x4;

__device__ inline unsigned short f2bf(float f) {
    unsigned u = __builtin_bit_cast(unsigned, f);
    u += 0x7fffu + ((u >> 16) & 1u);          // RNE
    return (unsigned short)(u >> 16);
}
__device__ inline float bf2f(unsigned short h) {
    return __builtin_bit_cast(float, ((unsigned)h) << 16);
}
__device__ inline unsigned short f2h(float f) {
    _Float16 h = (_Float16)f;
    return __builtin_bit_cast(unsigned short, h);
}
__device__ inline float h2f(unsigned short u) {
    return (float)__builtin_bit_cast(_Float16, u);
}

// LDS bf16 tile helpers with row-stride; XOR-swizzle flips element bits 3..5.
__device__ inline void lds_st16s(short* base, int row, int stride, int kcol, short8 v) {
    *reinterpret_cast<short8*>(&base[row * stride + (kcol ^ ((row & 7) << 3))]) = v;
}
__device__ inline short8 lds_ld16s(const short* base, int row, int stride, int kcol) {
    return *reinterpret_cast<const short8*>(&base[row * stride + (kcol ^ ((row & 7) << 3))]);
}

__device__ inline short8 cvt8(float4 a, float4 b) {
    short8 r;
    r[0] = (short)f2bf(a.x); r[1] = (short)f2bf(a.y);
    r[2] = (short)f2bf(a.z); r[3] = (short)f2bf(a.w);
    r[4] = (short)f2bf(b.x); r[5] = (short)f2bf(b.y);
    r[6] = (short)f2bf(b.z); r[7] = (short)f2bf(b.w);
    return r;
}

// ---------------------------------------------------------------------------
// Stage 1: value proj THEN off/attn proj, all 256 blocks run both phases
// (balanced: max 5+5 tile-units/block vs 9/12 with a static split).
// 1024 thr = 16 waves. B in VGPRs (8x short8/lane). LDS = A dbuf (2x16 KB).
// One barrier per tile; next tile's global loads issue before the MFMA.
// ---------------------------------------------------------------------------
__global__ __launch_bounds__(1024) void stage1(
    const float* __restrict__ enc, const float* __restrict__ Wval,
    const float* __restrict__ bval, unsigned short* __restrict__ vflat,
    const float* __restrict__ hidden, const float* __restrict__ Woff,
    const float* __restrict__ Wattn, const float* __restrict__ boff,
    const float* __restrict__ battn, unsigned short* __restrict__ proj)
{
    __shared__ __align__(16) short As[2][32 * 256];   // 2 x 16 KB

    const int tid  = threadIdx.x;
    const int lane = tid & 63, w = tid >> 6;
    const int l15  = lane & 15, l4 = lane >> 4;
    const int arow = tid >> 5, ak = (tid & 31) * 8;

    // ================= phase V: value projection =================
    {
        const int n = w * 16 + l15;
        short8 breg[8];
#pragma unroll
        for (int ks = 0; ks < 8; ++ks) {
            const float* s = &Wval[(size_t)n * K + ks * 32 + l4 * 8];
            breg[ks] = cvt8(*reinterpret_cast<const float4*>(s),
                            *reinterpret_cast<const float4*>(s + 4));
        }
        const float bv = bval[n];
        const int h = n >> 5, dd = n & 31;

        int t = blockIdx.x;
        float4 fa0, fa1;
        auto lda = [&](int tt) {
            const float* s = &enc[(size_t)(tt * 32 + arow) * K + ak];
            fa0 = *reinterpret_cast<const float4*>(s);
            fa1 = *reinterpret_cast<const float4*>(s + 4);
        };
        lda(t);
        lds_st16s(As[0], arow, 256, ak, cvt8(fa0, fa1));
        __syncthreads();
        int cur = 0;
        for (; t < NTILES; t += 256) {
            const bool more = (t + 256 < NTILES);
            if (more) lda(t + 256);            // overlaps MFMA below

            f32x4 acc0 = {0.f, 0.f, 0.f, 0.f}, acc1 = {0.f, 0.f, 0.f, 0.f};
#pragma unroll
            for (int ks = 0; ks < 8; ++ks) {
                const int kc = ks * 32 + l4 * 8;
                const short8 a0 = lds_ld16s(As[cur], l15, 256, kc);
                const short8 a1 = lds_ld16s(As[cur], 16 + l15, 256, kc);
                acc0 = __builtin_amdgcn_mfma_f32_16x16x32_bf16(a0, breg[ks], acc0, 0, 0, 0);
                acc1 = __builtin_amdgcn_mfma_f32_16x16x32_bf16(a1, breg[ks], acc1, 0, 0, 0);
            }
            const int m0 = t * 32;
#pragma unroll
            for (int r = 0; r < 4; ++r) {
                int m = m0 + l4 * 4 + r;
                int b_ = m / S, s_ = m - b_ * S;
                vflat[(((size_t)(b_ * NH + h)) * S + s_) * DH + dd] = f2bf(acc0[r] + bv);
                m += 16; b_ = m / S; s_ = m - b_ * S;
                vflat[(((size_t)(b_ * NH + h)) * S + s_) * DH + dd] = f2bf(acc1[r] + bv);
            }
            if (more) lds_st16s(As[cur ^ 1], arow, 256, ak, cvt8(fa0, fa1));
            __syncthreads();
            cur ^= 1;
        }
    }

    // ================= phase J: off+attn projection =================
    {
        const int nf = w >> 1, mh = w & 1;   // waves 0..11 compute
        const int n = nf * 16 + l15;         // 0..95 for w<12
        short8 breg[8];
        float bv = 0.f;
        if (w < 12) {
#pragma unroll
            for (int ks = 0; ks < 8; ++ks) {
                const float* s = (n < 64)
                    ? &Woff[(size_t)n * K + ks * 32 + l4 * 8]
                    : &Wattn[(size_t)(n - 64) * K + ks * 32 + l4 * 8];
                breg[ks] = cvt8(*reinterpret_cast<const float4*>(s),
                                *reinterpret_cast<const float4*>(s + 4));
            }
            bv = (n < 64) ? boff[n] : battn[n - 64];
        }

        int t = blockIdx.x;
        float4 fa0, fa1;
        auto lda = [&](int tt) {
            const float* s = &hidden[(size_t)(tt * 32 + arow) * K + ak];
            fa0 = *reinterpret_cast<const float4*>(s);
            fa1 = *reinterpret_cast<const float4*>(s + 4);
        };
        lda(t);
        lds_st16s(As[0], arow, 256, ak, cvt8(fa0, fa1));
        __syncthreads();
        int cur = 0;
        for (; t < NTILES; t += 256) {
            const bool more = (t + 256 < NTILES);
            if (more) lda(t + 256);

            if (w < 12) {
                f32x4 acc = {0.f, 0.f, 0.f, 0.f};
#pragma unroll
                for (int ks = 0; ks < 8; ++ks) {
                    const int kc = ks * 32 + l4 * 8;
                    const short8 a = lds_ld16s(As[cur], mh * 16 + l15, 256, kc);
                    acc = __builtin_amdgcn_mfma_f32_16x16x32_bf16(a, breg[ks], acc, 0, 0, 0);
                }
#pragma unroll
                for (int r = 0; r < 4; ++r) {
                    const int m = t * 32 + mh * 16 + l4 * 4 + r;
                    proj[(size_t)m * 96 + n] = f2h(acc[r] + bv);
                }
            }
            if (more) lds_st16s(As[cur ^ 1], arow, 256, ak, cvt8(fa0, fa1));
            __syncthreads();
            cur ^= 1;
        }
    }
}

// ---------------------------------------------------------------------------
// Kernel S: bilinear sampling + attention aggregation.
// 4 lanes per (b,h,q) group; lane owns 8 d-elements (16B gathers).
// p-loop split into two no-unroll halves: halves cidx/cw live range
// (VGPR <= 64 target -> 32 waves/CU for L2-gather latency hiding).
// 5000 blocks, XCD-swizzled -> each XCD works 4 contiguous (b,h) slices.
// ---------------------------------------------------------------------------
__global__ __launch_bounds__(256) void sample_agg(
    const unsigned short* __restrict__ vflat,  // [B*NH][S][DH] bf16
    const unsigned short* __restrict__ proj,   // [M][96] f16
    const float* __restrict__ ref,             // [M][2]
    unsigned short* __restrict__ tmp)          // [M][256] bf16
{
    const int nblk = gridDim.x;                // 5000, %8 == 0
    const int cpx  = nblk >> 3;
    const int swz  = (blockIdx.x & 7) * cpx + (blockIdx.x >> 3);

    const int lg   = threadIdx.x >> 2;   // 0..63
    const int lane = threadIdx.x & 3;
    const int d0   = lane * 8;

    const int g  = swz * 64 + lg;
    const int q  = g % Q;
    const int bh = g / Q;
    const int b  = bh >> 3;
    const int h  = bh & 7;

    const size_t bq = (size_t)b * Q + q;
    const float refx = ref[bq * 2 + 0];
    const float refy = ref[bq * 2 + 1];
    const unsigned short* pr = proj + bq * 96;

    // softmax -> ap[p]
    float ap[NP];
    {
        float l[NP];
#pragma unroll
        for (int p = 0; p < NP; ++p) l[p] = h2f(pr[64 + h * 4 + p]);
        const float mx = fmaxf(fmaxf(l[0], l[1]), fmaxf(l[2], l[3]));
        float esum = 0.f;
#pragma unroll
        for (int p = 0; p < NP; ++p) { ap[p] = __expf(l[p] - mx); esum += ap[p]; }
        const float inv = 1.f / esum;
#pragma unroll
        for (int p = 0; p < NP; ++p) ap[p] *= inv;
    }

    const unsigned short* vbase = vflat + (size_t)bh * (S * DH);

    float o[8];
#pragma unroll
    for (int j = 0; j < 8; ++j) o[j] = 0.f;

#pragma unroll 1
    for (int pp = 0; pp < 2; ++pp) {
        int   cidx[2][4];
        float cwv[2][4];
#pragma unroll
        for (int pi = 0; pi < 2; ++pi) {
            const int p = pp * 2 + pi;
            const float ox = h2f(pr[h * 8 + p * 2 + 0]);
            const float oy = h2f(pr[h * 8 + p * 2 + 1]);
            const float x = fmaf(refx, (float)WW, ox) - 0.5f;
            const float y = fmaf(refy, (float)HH, oy) - 0.5f;
            const float x0f = floorf(x), y0f = floorf(y);
            const float wx1 = x - x0f, wx0 = 1.f - wx1;
            const float wy1 = y - y0f, wy0 = 1.f - wy1;
            const int x0 = (int)x0f, y0 = (int)y0f;
            const bool vx0 = (x0 >= 0) && (x0 < WW);
            const bool vx1 = (x0 + 1 >= 0) && (x0 + 1 < WW);
            const bool vy0 = (y0 >= 0) && (y0 < HH);
            const bool vy1 = (y0 + 1 >= 0) && (y0 + 1 < HH);
            const int xi0 = min(max(x0, 0), WW - 1);
            const int xi1 = min(max(x0 + 1, 0), WW - 1);
            const int yi0 = min(max(y0, 0), HH - 1);
            const int yi1 = min(max(y0 + 1, 0), HH - 1);
            const float a = ap[p];
            cwv[pi][0] = a * wx0 * wy0 * ((vx0 && vy0) ? 1.f : 0.f);
            cwv[pi][1] = a * wx1 * wy0 * ((vx1 && vy0) ? 1.f : 0.f);
            cwv[pi][2] = a * wx0 * wy1 * ((vx0 && vy1) ? 1.f : 0.f);
            cwv[pi][3] = a * wx1 * wy1 * ((vx1 && vy1) ? 1.f : 0.f);
            cidx[pi][0] = (yi0 * WW + xi0) * DH + d0;
            cidx[pi][1] = (yi0 * WW + xi1) * DH + d0;
            cidx[pi][2] = (yi1 * WW + xi0) * DH + d0;
            cidx[pi][3] = (yi1 * WW + xi1) * DH + d0;
        }
#pragma unroll
        for (int pi = 0; pi < 2; ++pi) {
#pragma unroll
            for (int c = 0; c < 4; ++c) {
                const short8 v = *reinterpret_cast<const short8*>(&vbase[cidx[pi][c]]);
                const float wgt = cwv[pi][c];
#pragma unroll
                for (int j = 0; j < 8; ++j)
                    o[j] = fmaf(wgt, bf2f((unsigned short)v[j]), o[j]);
            }
        }
    }

    short8 ov;
#pragma unroll
    for (int j = 0; j < 8; ++j) ov[j] = (short)f2bf(o[j]);
    *reinterpret_cast<short8*>(&tmp[bq * 256 + h * 32 + d0]) = ov;
}

// ---------------------------------------------------------------------------
// Kernel O: out projection. 256 blocks x 1024 thr, persistent, W in VGPRs.
// A staged via global_load_lds (A already bf16): linear LDS dest (wave base
// + lane*16B), INVERSE-swizzled per-lane global source, swizzled ds_read.
// ---------------------------------------------------------------------------
__global__ __launch_bounds__(1024) void out_proj(
    const unsigned short* __restrict__ tmp, const float* __restrict__ Wo,
    const float* __restrict__ bo, float* __restrict__ out)
{
    __shared__ __align__(16) short As[2][32 * 256];   // 2 x 16 KB

    const int tid  = threadIdx.x;
    const int lane = tid & 63, w = tid >> 6;
    const int l15  = lane & 15, l4 = lane >> 4;
    const int arow = tid >> 5;                 // 0..31 (wave covers rows 2w,2w+1)

    const int n = w * 16 + l15;
    short8 breg[8];
#pragma unroll
    for (int ks = 0; ks < 8; ++ks) {
        const float* s = &Wo[(size_t)n * K + ks * 32 + l4 * 8];
        breg[ks] = cvt8(*reinterpret_cast<const float4*>(s),
                        *reinterpret_cast<const float4*>(s + 4));
    }
    const float bv = bo[n];

    // per-lane source chunk with inverse swizzle (involution of the read XOR)
    const int schunk = ((lane & 31) ^ (arow & 7)) * 8;   // element offset

    auto stage = [&](int tt, short* dstbuf) {
        const unsigned short* g = &tmp[(size_t)(tt * 32 + arow) * K + schunk];
        __builtin_amdgcn_global_load_lds(
            (const __attribute__((address_space(1))) unsigned int*)g,
            (__attribute__((address_space(3))) unsigned int*)(dstbuf + w * 512),
            16, 0, 0);
    };

    int t = blockIdx.x;
    stage(t, As[0]);
    __syncthreads();
    int cur = 0;
    for (; t < NTILES; t += 256) {
        const bool more = (t + 256 < NTILES);
        if (more) stage(t + 256, As[cur ^ 1]);   // in flight across the MFMA

        f32x4 acc0 = {0.f, 0.f, 0.f, 0.f}, acc1 = {0.f, 0.f, 0.f, 0.f};
#pragma unroll
        for (int ks = 0; ks < 8; ++ks) {
            const int kc = ks * 32 + l4 * 8;
            const short8 a0 = lds_ld16s(As[cur], l15, 256, kc);
            const short8 a1 = lds_ld16s(As[cur], 16 + l15, 256, kc);
            acc0 = __builtin_amdgcn_mfma_f32_16x16x32_bf16(a0, breg[ks], acc0, 0, 0, 0);
            acc1 = __builtin_amdgcn_mfma_f32_16x16x32_bf16(a1, breg[ks], acc1, 0, 0, 0);
        }
        const int m0 = t * 32;
#pragma unroll
        for (int r = 0; r < 4; ++r) {
            const int m = m0 + l4 * 4 + r;
            out[(size_t)m * K + n] = acc0[r] + bv;
            out[(size_t)(m + 16) * K + n] = acc1[r] + bv;
        }
        __syncthreads();
        cur ^= 1;
    }
}

// ---------------------------------------------------------------------------
extern "C" void kernel_launch(void* const* d_in, const int* in_sizes, int n_in,
                              void* d_out, int out_size, void* d_ws, size_t ws_size,
                              hipStream_t stream)
{
    const float* hidden = (const float*)d_in[0];
    const float* enc    = (const float*)d_in[1];
    const float* refp   = (const float*)d_in[2];
    const float* W_off  = (const float*)d_in[4];
    const float* b_off  = (const float*)d_in[5];
    const float* W_attn = (const float*)d_in[6];
    const float* b_attn = (const float*)d_in[7];
    const float* W_val  = (const float*)d_in[8];
    const float* b_val  = (const float*)d_in[9];
    const float* W_out  = (const float*)d_in[10];
    const float* b_out  = (const float*)d_in[11];
    float* out = (float*)d_out;

    // workspace (u16 elements): vflat | proj | tmp
    unsigned short* vflat = (unsigned short*)d_ws;     // 10,240,000
    unsigned short* proj  = vflat + (size_t)10240000;  //  3,840,000
    unsigned short* tmp   = proj + (size_t)3840000;    // 10,240,000

    // 1) value proj then off/attn proj, balanced persistent launch
    stage1<<<256, 1024, 0, stream>>>(
        enc, W_val, b_val, vflat, hidden, W_off, W_attn, b_off, b_attn, proj);

    // 2) bilinear sampling + softmax aggregation -> tmp bf16 [M][256]
    sample_agg<<<5000, 256, 0, stream>>>(vflat, proj, refp, tmp);

    // 3) out projection (reg-B persistent, global_load_lds A dbuf) -> f32
    out_proj<<<256, 1024, 0, stream>>>(tmp, W_out, b_out, out);
}